// Round 12
// baseline (50.532 us; speedup 1.0000x reference)
//
#include <hip/hip_runtime.h>
#include <hip/hip_bf16.h>

// RegionCodecDict — DIAGNOSTIC ROUND: codec work duplicated 2x (blocks 512..1023
// write to a scratch mirror) so the codec dispatch exceeds the harness's ~40us
// fill dispatches and surfaces its own rocprof counters. Per-block behavior is
// byte-identical to the r11 region-per-wave kernel. Output unchanged.
//
// ws layout:
//   pos    : int[1024]               @ 0
//   c      : float[8*128]            @ 4096
//   MTp    : ushort(bf16)[8*128*128] @ 8192     wave-tiled chunks
//   part   : float[32*16384]         @ 270336
//   part_c : float[32*8*128]         @ 2367488
//   mirror : float[8192*1024]        @ 4194304  (diagnostic write target)

typedef __attribute__((ext_vector_type(8))) short bf16x8;
typedef __attribute__((ext_vector_type(4))) float f32x4;
typedef __attribute__((ext_vector_type(4))) short s16x4;

#define NREG 8
#define NRD  128
#define DD   512
#define NN   1024
#define ROWS 16

static __device__ __forceinline__ unsigned short f2bf(float x) {
  union { float f; unsigned u; } v; v.f = x;
  unsigned r = v.u + 0x7fffu + ((v.u >> 16) & 1u);   // RNE
  return (unsigned short)(r >> 16);
}
static __device__ __forceinline__ unsigned short f2bf_hw(float x) {
  union { __hip_bfloat16 h; unsigned short u; } c;
  c.h = __float2bfloat16(x);
  return c.u;
}
static __device__ __forceinline__ float bf2f(unsigned short b) {
  union { unsigned u; float f; } v; v.u = ((unsigned)b) << 16;
  return v.f;
}

// ---------- prep1: 32 GEMM-partial blocks (r x d-chunk) + 1 pos block ----------
__global__ __launch_bounds__(256) void prep1_kernel(
    const float* __restrict__ W_enc, const float* __restrict__ b_enc,
    const float* __restrict__ W_dec, const int* __restrict__ idx,
    int* __restrict__ pos_ws, float* __restrict__ part,
    float* __restrict__ part_c)
{
  __shared__ unsigned short As[128 * 128];   // As[n][d^sw(n)]  (Wd^T slice)
  __shared__ unsigned short Bs[128 * 128];   // Bs[k][d^sw(k)]  (We slice)
  int blk = blockIdx.x, t = threadIdx.x;

  if (blk < 32) {
    int r = blk >> 2, dc = blk & 3, d0 = dc * 128;
    const float* We = W_enc + (size_t)r * NRD * DD;
    const float* Wd = W_dec + (size_t)r * DD * NRD;
    const float* be = b_enc + (size_t)r * DD;

    // stage As: transpose-scatter Wd[d0+dl][n] -> As[n][dl^sw]; fuse c partials
    int n4 = (t & 31) * 4, dlb = t >> 5;     // dlb in 0..7
    float c0 = 0.f, c1 = 0.f, c2 = 0.f, c3 = 0.f;
    #pragma unroll
    for (int p = 0; p < 16; ++p) {
      int dl = dlb + p * 8;
      float4 v = *(const float4*)&Wd[(size_t)(d0 + dl) * NRD + n4];
      float bev = be[d0 + dl];
      As[(n4 + 0) * 128 + (dl ^ (((n4 + 0) & 7) << 3))] = f2bf(v.x);
      As[(n4 + 1) * 128 + (dl ^ (((n4 + 1) & 7) << 3))] = f2bf(v.y);
      As[(n4 + 2) * 128 + (dl ^ (((n4 + 2) & 7) << 3))] = f2bf(v.z);
      As[(n4 + 3) * 128 + (dl ^ (((n4 + 3) & 7) << 3))] = f2bf(v.w);
      c0 += v.x * bev; c1 += v.y * bev; c2 += v.z * bev; c3 += v.w * bev;
    }
    {
      float4 cv; cv.x = c0; cv.y = c1; cv.z = c2; cv.w = c3;
      *(float4*)&part_c[((size_t)(r * 4 + dc) * 8 + dlb) * 128 + n4] = cv;
    }
    // stage Bs: straight copy We[k][d0..d0+128]
    #pragma unroll
    for (int i = 0; i < 8; ++i) {
      int cid = t + i * 256;
      int k = cid >> 4, dq = (cid & 15) * 8;
      const float* src = &We[(size_t)k * DD + d0 + dq];
      float4 u = *(const float4*)src;
      float4 u2 = *(const float4*)(src + 4);
      bf16x8 pk;
      pk[0] = (short)f2bf(u.x);  pk[1] = (short)f2bf(u.y);
      pk[2] = (short)f2bf(u.z);  pk[3] = (short)f2bf(u.w);
      pk[4] = (short)f2bf(u2.x); pk[5] = (short)f2bf(u2.y);
      pk[6] = (short)f2bf(u2.z); pk[7] = (short)f2bf(u2.w);
      *(bf16x8*)&Bs[k * 128 + (dq ^ ((k & 7) << 3))] = pk;
    }
    __syncthreads();

    int lane = t & 63, w = t >> 6;
    int arow = lane & 15, ag = lane >> 4;
    f32x4 acc[8][2];
    #pragma unroll
    for (int i = 0; i < 8; ++i) {
      acc[i][0] = (f32x4){0.f, 0.f, 0.f, 0.f};
      acc[i][1] = (f32x4){0.f, 0.f, 0.f, 0.f};
    }
    #pragma unroll
    for (int nt = 0; nt < 8; ++nt) {
      int nl = nt * 16 + arow, asw = (nl & 7) << 3;
      bf16x8 a[4];
      #pragma unroll
      for (int ks = 0; ks < 4; ++ks)
        a[ks] = *(const bf16x8*)&As[nl * 128 + ((ks * 32 + ag * 8) ^ asw)];
      #pragma unroll
      for (int kt = 0; kt < 2; ++kt) {
        int kk = w * 32 + kt * 16 + arow, bsw = (kk & 7) << 3;
        #pragma unroll
        for (int ks = 0; ks < 4; ++ks) {
          bf16x8 b = *(const bf16x8*)&Bs[kk * 128 + ((ks * 32 + ag * 8) ^ bsw)];
          acc[nt][kt] = __builtin_amdgcn_mfma_f32_16x16x32_bf16(a[ks], b, acc[nt][kt], 0, 0, 0);
        }
      }
    }
    float* dst = part + (size_t)(r * 4 + dc) * 16384;
    #pragma unroll
    for (int nt = 0; nt < 8; ++nt)
      #pragma unroll
      for (int kt = 0; kt < 2; ++kt)
        #pragma unroll
        for (int v = 0; v < 4; ++v)
          dst[(nt * 16 + ag * 4 + v) * 128 + (w * 32 + kt * 16 + arow)] = acc[nt][kt][v];
  } else {
    // pos block
    #pragma unroll
    for (int i = 0; i < 4; ++i) {
      int q = t * 4 + i;
      pos_ws[idx[q]] = q;
    }
  }
}

// ---------- prep2: reduce partials -> MTp (bf16, wave-tiled layout) and c (f32) ----------
__global__ __launch_bounds__(256) void prep2_kernel(
    const float* __restrict__ part, const float* __restrict__ part_c,
    const float* __restrict__ b_dec, unsigned short* __restrict__ MTp,
    float* __restrict__ c_ws)
{
  int blk = blockIdx.x, t = threadIdx.x;
  if (blk < 128) {
    int e0 = (blk * 256 + t) * 4;
    int r = e0 >> 14, off = e0 & 16383;
    int n = off >> 7, k0 = off & 127;
    const float* p = part + (size_t)r * 4 * 16384 + off;
    float4 s0 = *(const float4*)&p[0];
    float4 s1 = *(const float4*)&p[16384];
    float4 s2 = *(const float4*)&p[32768];
    float4 s3 = *(const float4*)&p[49152];
    s16x4 o;
    o.x = (short)f2bf(s0.x + s1.x + s2.x + s3.x);
    o.y = (short)f2bf(s0.y + s1.y + s2.y + s3.y);
    o.z = (short)f2bf(s0.z + s1.z + s2.z + s3.z);
    o.w = (short)f2bf(s0.w + s1.w + s2.w + s3.w);
    int w = n >> 4, arow = n & 15, kt = k0 >> 5, ag = (k0 >> 3) & 3, sub = k0 & 7;
    int chunk = (r * 32 + w * 4 + kt) * 64 + (arow * 4 + ag);
    *(s16x4*)&MTp[chunk * 8 + sub] = o;
  } else if (blk < 132) {
    int e = (blk - 128) * 256 + t;
    int n = e & 127;
    int r = e >> 7;
    float s = b_dec[e];
    #pragma unroll
    for (int dc = 0; dc < 4; ++dc)
      #pragma unroll
      for (int g = 0; g < 8; ++g)
        s += part_c[((size_t)(r * 4 + dc) * 8 + g) * 128 + n];
    c_ws[e] = s;
  }
}

// ---------- main codec (DIAGNOSTIC 2x): region-per-wave, 512 thr, 32KB LDS ----------
// tile = blockIdx.x & 511; blocks >= 512 write identical results to `mirror`.
__global__ __launch_bounds__(512) void codec_kernel(
    const float* __restrict__ spikes, const int* __restrict__ pos_ws,
    const float* __restrict__ c_ws, const unsigned short* __restrict__ MTp,
    float* __restrict__ out, float* __restrict__ mirror)
{
  __shared__ unsigned short Xs[ROWS * NN];   // 32KB, region-permuted, row-swizzled
  int t = threadIdx.x;
  int w = t >> 6, lane = t & 63;             // 8 waves; wave w <-> region w
  int arow = lane & 15, ag = lane >> 4;
  int asw = (arow & 7) << 3;
  int lanechunk = arow * 4 + ag;
  int tile = blockIdx.x & 511;
  float* dst = (blockIdx.x < 512) ? out : mirror;
  size_t row0 = (size_t)tile * ROWS;

  // register-cached permutation and per-col bias (8 col-tiles of region w)
  int4 p4c[4];
  #pragma unroll
  for (int ch = 0; ch < 4; ++ch)
    p4c[ch] = *(const int4*)&pos_ws[ch * 256 + lane * 4];
  float cvr[8];
  #pragma unroll
  for (int j = 0; j < 8; ++j)
    cvr[j] = c_ws[w * 128 + j * 16 + arow];

  // ---- stage: wave w stages rows 2w, 2w+1; coalesced float4, permuted bf16 scatter
  #pragma unroll
  for (int ch = 0; ch < 4; ++ch) {
    int j = ch * 256 + lane * 4;
    int4 p4 = p4c[ch];
    #pragma unroll
    for (int rl = 0; rl < 2; ++rl) {
      int row = w * 2 + rl;
      float4 v = *(const float4*)&spikes[(row0 + row) * NN + j];
      int base = row * NN, sw = (row & 7) << 3;
      Xs[base + (p4.x ^ sw)] = f2bf_hw(v.x);
      Xs[base + (p4.y ^ sw)] = f2bf_hw(v.y);
      Xs[base + (p4.z ^ sw)] = f2bf_hw(v.z);
      Xs[base + (p4.w ^ sw)] = f2bf_hw(v.w);
    }
  }
  __syncthreads();

  // ---- region w, all 128 cols: A read ONCE, 8 col-tiles {B-load, MFMA, write}
  bf16x8 a[4];
  #pragma unroll
  for (int kt = 0; kt < 4; ++kt)
    a[kt] = *(const bf16x8*)&Xs[arow * NN + ((w * 128 + kt * 32 + ag * 8) ^ asw)];
  const bf16x8* Bb = (const bf16x8*)MTp;
  #pragma unroll
  for (int j = 0; j < 8; ++j) {
    bf16x8 b[4];
    #pragma unroll
    for (int kt = 0; kt < 4; ++kt)
      b[kt] = Bb[(w * 32 + j * 4 + kt) * 64 + lanechunk];
    f32x4 acc = {0.f, 0.f, 0.f, 0.f};
    #pragma unroll
    for (int kt = 0; kt < 4; ++kt)
      acc = __builtin_amdgcn_mfma_f32_16x16x32_bf16(a[kt], b[kt], acc, 0, 0, 0);
    int coln = w * 128 + j * 16 + arow;      // D[i][col]: i = 4*ag+v, col = j*16 + lane%16
    #pragma unroll
    for (int v = 0; v < 4; ++v) {
      int i = ag * 4 + v, isw = (i & 7) << 3;
      Xs[i * NN + (coln ^ isw)] = f2bf_hw(acc[v] + cvr[j]);
    }
  }
  __syncthreads();

  // ---- writeback: pos-gather rows 2w, 2w+1; coalesced float4 stores
  #pragma unroll
  for (int ch = 0; ch < 4; ++ch) {
    int j = ch * 256 + lane * 4;
    int4 p4 = p4c[ch];
    #pragma unroll
    for (int rl = 0; rl < 2; ++rl) {
      int row = w * 2 + rl;
      int base = row * NN, sw = (row & 7) << 3;
      float4 v;
      v.x = bf2f(Xs[base + (p4.x ^ sw)]);
      v.y = bf2f(Xs[base + (p4.y ^ sw)]);
      v.z = bf2f(Xs[base + (p4.z ^ sw)]);
      v.w = bf2f(Xs[base + (p4.w ^ sw)]);
      *(float4*)&dst[(row0 + row) * NN + j] = v;
    }
  }
}

extern "C" void kernel_launch(void* const* d_in, const int* in_sizes, int n_in,
                              void* d_out, int out_size, void* d_ws, size_t ws_size,
                              hipStream_t stream) {
  const float* spikes = (const float*)d_in[0];
  const float* W_enc  = (const float*)d_in[1];
  const float* b_enc  = (const float*)d_in[2];
  const float* W_dec  = (const float*)d_in[3];
  const float* b_dec  = (const float*)d_in[4];
  const int*   idx    = (const int*)d_in[5];
  float* out = (float*)d_out;

  char* ws = (char*)d_ws;
  int*            pos_ws  = (int*)ws;
  float*          c_ws    = (float*)(ws + 4096);
  unsigned short* MTp_ws  = (unsigned short*)(ws + 8192);
  float*          part    = (float*)(ws + 270336);
  float*          part_c  = (float*)(ws + 2367488);
  float*          mirror  = (float*)(ws + 4194304);

  prep1_kernel<<<33, 256, 0, stream>>>(W_enc, b_enc, W_dec, idx,
                                       pos_ws, part, part_c);
  prep2_kernel<<<132, 256, 0, stream>>>(part, part_c, b_dec, MTp_ws, c_ws);
  codec_kernel<<<1024, 512, 0, stream>>>(spikes, pos_ws, c_ws, MTp_ws, out, mirror);
}

// Round 13
// 31.913 us; speedup vs baseline: 1.5834x; 1.5834x over previous
//
#include <hip/hip_runtime.h>
#include <hip/hip_bf16.h>

// RegionCodecDict: out[b,t,idx[r][n]] = sum_m spikes[b,t,idx[r][m]] * M[r][m][n] + c[r][n]
// where M[r] = W_enc[r] @ W_dec[r]  (128x128), c[r] = b_enc[r] @ W_dec[r] + b_dec[r]
// (the reference is purely linear between the two einsums, so they collapse).
//
// ws layout (~2.4 MB):
//   pos    : int[1024]               @ 0        inverse permutation
//   c      : float[8*128]            @ 4096
//   MTp    : ushort(bf16)[8*128*128] @ 8192     wave-tiled: chunk (r*32+j*4+kt)*64+(arow*4+ag)
//   part   : float[32*16384]         @ 270336   per-(r,dc) 128x128 f32 GEMM partials
//   part_c : float[32*8*128]         @ 2367488  per-(r,dc,dlb) c partials

typedef __attribute__((ext_vector_type(8))) short bf16x8;
typedef __attribute__((ext_vector_type(4))) float f32x4;
typedef __attribute__((ext_vector_type(4))) short s16x4;

#define NREG 8
#define NRD  128
#define DD   512
#define NN   1024
#define ROWS 16

static __device__ __forceinline__ unsigned short f2bf(float x) {
  union { float f; unsigned u; } v; v.f = x;
  unsigned r = v.u + 0x7fffu + ((v.u >> 16) & 1u);   // RNE
  return (unsigned short)(r >> 16);
}
static __device__ __forceinline__ unsigned short f2bf_hw(float x) {
  union { __hip_bfloat16 h; unsigned short u; } c;
  c.h = __float2bfloat16(x);
  return c.u;
}
static __device__ __forceinline__ float bf2f(unsigned short b) {
  union { unsigned u; float f; } v; v.u = ((unsigned)b) << 16;
  return v.f;
}

// ---------- prep1: 32 GEMM-partial blocks (r x d-chunk) + 1 pos block ----------
__global__ __launch_bounds__(256) void prep1_kernel(
    const float* __restrict__ W_enc, const float* __restrict__ b_enc,
    const float* __restrict__ W_dec, const int* __restrict__ idx,
    int* __restrict__ pos_ws, float* __restrict__ part,
    float* __restrict__ part_c)
{
  __shared__ unsigned short As[128 * 128];   // As[n][d^sw(n)]  (Wd^T slice)
  __shared__ unsigned short Bs[128 * 128];   // Bs[k][d^sw(k)]  (We slice)
  int blk = blockIdx.x, t = threadIdx.x;

  if (blk < 32) {
    int r = blk >> 2, dc = blk & 3, d0 = dc * 128;
    const float* We = W_enc + (size_t)r * NRD * DD;
    const float* Wd = W_dec + (size_t)r * DD * NRD;
    const float* be = b_enc + (size_t)r * DD;

    // stage As: transpose-scatter Wd[d0+dl][n] -> As[n][dl^sw]; fuse c partials
    int n4 = (t & 31) * 4, dlb = t >> 5;     // dlb in 0..7
    float c0 = 0.f, c1 = 0.f, c2 = 0.f, c3 = 0.f;
    #pragma unroll
    for (int p = 0; p < 16; ++p) {
      int dl = dlb + p * 8;
      float4 v = *(const float4*)&Wd[(size_t)(d0 + dl) * NRD + n4];
      float bev = be[d0 + dl];
      As[(n4 + 0) * 128 + (dl ^ (((n4 + 0) & 7) << 3))] = f2bf(v.x);
      As[(n4 + 1) * 128 + (dl ^ (((n4 + 1) & 7) << 3))] = f2bf(v.y);
      As[(n4 + 2) * 128 + (dl ^ (((n4 + 2) & 7) << 3))] = f2bf(v.z);
      As[(n4 + 3) * 128 + (dl ^ (((n4 + 3) & 7) << 3))] = f2bf(v.w);
      c0 += v.x * bev; c1 += v.y * bev; c2 += v.z * bev; c3 += v.w * bev;
    }
    {
      float4 cv; cv.x = c0; cv.y = c1; cv.z = c2; cv.w = c3;
      *(float4*)&part_c[((size_t)(r * 4 + dc) * 8 + dlb) * 128 + n4] = cv;
    }
    // stage Bs: straight copy We[k][d0..d0+128]
    #pragma unroll
    for (int i = 0; i < 8; ++i) {
      int cid = t + i * 256;
      int k = cid >> 4, dq = (cid & 15) * 8;
      const float* src = &We[(size_t)k * DD + d0 + dq];
      float4 u = *(const float4*)src;
      float4 u2 = *(const float4*)(src + 4);
      bf16x8 pk;
      pk[0] = (short)f2bf(u.x);  pk[1] = (short)f2bf(u.y);
      pk[2] = (short)f2bf(u.z);  pk[3] = (short)f2bf(u.w);
      pk[4] = (short)f2bf(u2.x); pk[5] = (short)f2bf(u2.y);
      pk[6] = (short)f2bf(u2.z); pk[7] = (short)f2bf(u2.w);
      *(bf16x8*)&Bs[k * 128 + (dq ^ ((k & 7) << 3))] = pk;
    }
    __syncthreads();

    int lane = t & 63, w = t >> 6;
    int arow = lane & 15, ag = lane >> 4;
    f32x4 acc[8][2];
    #pragma unroll
    for (int i = 0; i < 8; ++i) {
      acc[i][0] = (f32x4){0.f, 0.f, 0.f, 0.f};
      acc[i][1] = (f32x4){0.f, 0.f, 0.f, 0.f};
    }
    #pragma unroll
    for (int nt = 0; nt < 8; ++nt) {
      int nl = nt * 16 + arow, asw = (nl & 7) << 3;
      bf16x8 a[4];
      #pragma unroll
      for (int ks = 0; ks < 4; ++ks)
        a[ks] = *(const bf16x8*)&As[nl * 128 + ((ks * 32 + ag * 8) ^ asw)];
      #pragma unroll
      for (int kt = 0; kt < 2; ++kt) {
        int kk = w * 32 + kt * 16 + arow, bsw = (kk & 7) << 3;
        #pragma unroll
        for (int ks = 0; ks < 4; ++ks) {
          bf16x8 b = *(const bf16x8*)&Bs[kk * 128 + ((ks * 32 + ag * 8) ^ bsw)];
          acc[nt][kt] = __builtin_amdgcn_mfma_f32_16x16x32_bf16(a[ks], b, acc[nt][kt], 0, 0, 0);
        }
      }
    }
    float* dst = part + (size_t)(r * 4 + dc) * 16384;
    #pragma unroll
    for (int nt = 0; nt < 8; ++nt)
      #pragma unroll
      for (int kt = 0; kt < 2; ++kt)
        #pragma unroll
        for (int v = 0; v < 4; ++v)
          dst[(nt * 16 + ag * 4 + v) * 128 + (w * 32 + kt * 16 + arow)] = acc[nt][kt][v];
  } else {
    // pos block
    #pragma unroll
    for (int i = 0; i < 4; ++i) {
      int q = t * 4 + i;
      pos_ws[idx[q]] = q;
    }
  }
}

// ---------- prep2: reduce partials -> MTp (bf16, wave-tiled layout) and c (f32) ----------
__global__ __launch_bounds__(256) void prep2_kernel(
    const float* __restrict__ part, const float* __restrict__ part_c,
    const float* __restrict__ b_dec, unsigned short* __restrict__ MTp,
    float* __restrict__ c_ws)
{
  int blk = blockIdx.x, t = threadIdx.x;
  if (blk < 128) {
    int e0 = (blk * 256 + t) * 4;
    int r = e0 >> 14, off = e0 & 16383;
    int n = off >> 7, k0 = off & 127;
    const float* p = part + (size_t)r * 4 * 16384 + off;
    float4 s0 = *(const float4*)&p[0];
    float4 s1 = *(const float4*)&p[16384];
    float4 s2 = *(const float4*)&p[32768];
    float4 s3 = *(const float4*)&p[49152];
    s16x4 o;
    o.x = (short)f2bf(s0.x + s1.x + s2.x + s3.x);
    o.y = (short)f2bf(s0.y + s1.y + s2.y + s3.y);
    o.z = (short)f2bf(s0.z + s1.z + s2.z + s3.z);
    o.w = (short)f2bf(s0.w + s1.w + s2.w + s3.w);
    int w = n >> 4, arow = n & 15, kt = k0 >> 5, ag = (k0 >> 3) & 3, sub = k0 & 7;
    int chunk = (r * 32 + w * 4 + kt) * 64 + (arow * 4 + ag);
    *(s16x4*)&MTp[chunk * 8 + sub] = o;
  } else if (blk < 132) {
    int e = (blk - 128) * 256 + t;
    int n = e & 127;
    int r = e >> 7;
    float s = b_dec[e];
    #pragma unroll
    for (int dc = 0; dc < 4; ++dc)
      #pragma unroll
      for (int g = 0; g < 8; ++g)
        s += part_c[((size_t)(r * 4 + dc) * 8 + g) * 128 + n];
    c_ws[e] = s;
  }
}

// ---------- main codec: region-per-wave + deep in-flight memory ----------
// Latency plan: (1) all 8 stage HBM loads issued as one batch into regs,
// (2) first 2 col-tiles' B loads (L2) issued BEFORE the stage barrier so their
// latency hides under the stage loads, (3) depth-2 rolling B double-buffer
// through the fully-unrolled j-loop keeps 8 B-loads in flight during MFMAs.
__global__ __launch_bounds__(512, 4) void codec_kernel(
    const float* __restrict__ spikes, const int* __restrict__ pos_ws,
    const float* __restrict__ c_ws, const unsigned short* __restrict__ MTp,
    float* __restrict__ out)
{
  __shared__ unsigned short Xs[ROWS * NN];   // 32KB, region-permuted, row-swizzled
  int t = threadIdx.x;
  int w = t >> 6, lane = t & 63;             // 8 waves; wave w <-> region w
  int arow = lane & 15, ag = lane >> 4;
  int asw = (arow & 7) << 3;
  int lanechunk = arow * 4 + ag;
  size_t row0 = (size_t)blockIdx.x * ROWS;
  const bf16x8* Bb = (const bf16x8*)MTp;

  // register-cached permutation and per-col bias (8 col-tiles of region w)
  int4 p4c[4];
  #pragma unroll
  for (int ch = 0; ch < 4; ++ch)
    p4c[ch] = *(const int4*)&pos_ws[ch * 256 + lane * 4];
  float cvr[8];
  #pragma unroll
  for (int j = 0; j < 8; ++j)
    cvr[j] = c_ws[w * 128 + j * 16 + arow];

  // ---- issue ALL stage loads as one batch (rows 2w, 2w+1; coalesced float4)
  float4 sv[4][2];
  #pragma unroll
  for (int ch = 0; ch < 4; ++ch)
    #pragma unroll
    for (int rl = 0; rl < 2; ++rl)
      sv[ch][rl] = *(const float4*)&spikes[(row0 + w * 2 + rl) * NN + ch * 256 + lane * 4];

  // ---- hoist B col-tiles 0,1 (L2): latency hides under the stage loads above
  bf16x8 bb[2][4];
  #pragma unroll
  for (int kt = 0; kt < 4; ++kt)
    bb[0][kt] = Bb[(w * 32 + 0 * 4 + kt) * 64 + lanechunk];
  #pragma unroll
  for (int kt = 0; kt < 4; ++kt)
    bb[1][kt] = Bb[(w * 32 + 1 * 4 + kt) * 64 + lanechunk];

  // ---- scatter staged rows into permuted LDS layout
  #pragma unroll
  for (int ch = 0; ch < 4; ++ch) {
    int4 p4 = p4c[ch];
    #pragma unroll
    for (int rl = 0; rl < 2; ++rl) {
      int row = w * 2 + rl;
      int base = row * NN, sw = (row & 7) << 3;
      float4 v = sv[ch][rl];
      Xs[base + (p4.x ^ sw)] = f2bf_hw(v.x);
      Xs[base + (p4.y ^ sw)] = f2bf_hw(v.y);
      Xs[base + (p4.z ^ sw)] = f2bf_hw(v.z);
      Xs[base + (p4.w ^ sw)] = f2bf_hw(v.w);
    }
  }
  __syncthreads();

  // ---- region w, all 128 cols: A read once; rolling depth-2 B prefetch
  bf16x8 a[4];
  #pragma unroll
  for (int kt = 0; kt < 4; ++kt)
    a[kt] = *(const bf16x8*)&Xs[arow * NN + ((w * 128 + kt * 32 + ag * 8) ^ asw)];
  #pragma unroll
  for (int j = 0; j < 8; ++j) {
    f32x4 acc = {0.f, 0.f, 0.f, 0.f};
    #pragma unroll
    for (int kt = 0; kt < 4; ++kt)
      acc = __builtin_amdgcn_mfma_f32_16x16x32_bf16(a[kt], bb[j & 1][kt], acc, 0, 0, 0);
    if (j + 2 < 8) {                          // refill the buffer just consumed
      #pragma unroll
      for (int kt = 0; kt < 4; ++kt)
        bb[j & 1][kt] = Bb[(w * 32 + (j + 2) * 4 + kt) * 64 + lanechunk];
    }
    int coln = w * 128 + j * 16 + arow;       // D[i][col]: i = 4*ag+v, col = j*16 + lane%16
    #pragma unroll
    for (int v = 0; v < 4; ++v) {
      int i = ag * 4 + v, isw = (i & 7) << 3;
      Xs[i * NN + (coln ^ isw)] = f2bf_hw(acc[v] + cvr[j]);
    }
  }
  __syncthreads();

  // ---- writeback: pos-gather rows 2w, 2w+1; coalesced float4 stores
  #pragma unroll
  for (int ch = 0; ch < 4; ++ch) {
    int j = ch * 256 + lane * 4;
    int4 p4 = p4c[ch];
    #pragma unroll
    for (int rl = 0; rl < 2; ++rl) {
      int row = w * 2 + rl;
      int base = row * NN, sw = (row & 7) << 3;
      float4 v;
      v.x = bf2f(Xs[base + (p4.x ^ sw)]);
      v.y = bf2f(Xs[base + (p4.y ^ sw)]);
      v.z = bf2f(Xs[base + (p4.z ^ sw)]);
      v.w = bf2f(Xs[base + (p4.w ^ sw)]);
      *(float4*)&out[(row0 + row) * NN + j] = v;
    }
  }
}

extern "C" void kernel_launch(void* const* d_in, const int* in_sizes, int n_in,
                              void* d_out, int out_size, void* d_ws, size_t ws_size,
                              hipStream_t stream) {
  const float* spikes = (const float*)d_in[0];
  const float* W_enc  = (const float*)d_in[1];
  const float* b_enc  = (const float*)d_in[2];
  const float* W_dec  = (const float*)d_in[3];
  const float* b_dec  = (const float*)d_in[4];
  const int*   idx    = (const int*)d_in[5];
  float* out = (float*)d_out;

  char* ws = (char*)d_ws;
  int*            pos_ws  = (int*)ws;
  float*          c_ws    = (float*)(ws + 4096);
  unsigned short* MTp_ws  = (unsigned short*)(ws + 8192);
  float*          part    = (float*)(ws + 270336);
  float*          part_c  = (float*)(ws + 2367488);

  prep1_kernel<<<33, 256, 0, stream>>>(W_enc, b_enc, W_dec, idx,
                                       pos_ws, part, part_c);
  prep2_kernel<<<132, 256, 0, stream>>>(part, part_c, b_dec, MTp_ws, c_ws);
  codec_kernel<<<8192 / ROWS, 512, 0, stream>>>(spikes, pos_ws, c_ws, MTp_ws, out);
}